// Round 5
// baseline (538.634 us; speedup 1.0000x reference)
//
#include <hip/hip_runtime.h>
#include <cstdint>
#include <cstddef>

// Problem constants (from reference setup_inputs)
constexpr int P  = 200000;   // points
constexpr int C  = 256;      // clicks
constexpr int NC = 200;      // classes
#define DICE_TH 0.4f
#define CLS_TH  0.5f
#define LN_EPS  1e-5f

// gram split-K config: KC * NCHUNK == P, KC % 32 == 0
constexpr int KC = 800;
constexpr int NCHUNK = 250;
constexpr int NSTEP = KC / 32;        // 25
constexpr int GP_CHUNK = 3 * 16384;   // floats per chunk (3 tile types)

// workspace byte offsets (Gp partials first; total ~49.9 MB)
constexpr size_t WS_GP      = 0;                         // 250*49152*4 = 49,152,000
constexpr size_t WS_G       = 49152000;                  // 262144
constexpr size_t WS_S       = WS_G + 262144;             // 1024
constexpr size_t WS_PROW    = WS_S + 1024;               // 204800
constexpr size_t WS_PT      = WS_PROW + 204800;          // 204800
constexpr size_t WS_COND    = WS_PT + 204800;            // 8192
constexpr size_t WS_MSTART  = WS_COND + 8192;            // 1028
constexpr size_t WS_MEMBERS = WS_MSTART + 1280;          // 1024

typedef float floatx16 __attribute__((ext_vector_type(16)));
typedef __bf16 bf16x8 __attribute__((ext_vector_type(8)));
typedef unsigned short ushort8 __attribute__((ext_vector_type(8)));

__device__ __forceinline__ unsigned short f2bf(float f) {
  unsigned u = __builtin_bit_cast(unsigned, f);
  unsigned r = u + 0x7FFFu + ((u >> 16) & 1u);   // RNE
  return (unsigned short)(r >> 16);
}

// ---------------------------------------------------------------------------
// Kernel 1: G = M^T M via bf16 MFMA (fp32 accumulate), split-K, no atomics on
// G (per-chunk partials streamed to Gp). v4: TWO-step register prefetch so
// each thread keeps 16-32 loads in flight across the MFMA sections.
// Symmetric: only tiles (0,0),(0,1),(1,1) computed; reduce_g writes mirror.
// LDS layout: [col][k] bf16, row stride 40 -> conflict-free ds_read_b128.
// ---------------------------------------------------------------------------
constexpr int LDA = 40;

__global__ __launch_bounds__(256, 3) void gram_mfma_kernel(
    const float* __restrict__ M, float* __restrict__ Gp,
    float* __restrict__ s) {
  __shared__ unsigned short Abf[128 * LDA];
  __shared__ unsigned short Bbf[128 * LDA];

  const int type = blockIdx.x;              // 0:(0,0) 1:(0,128) 2:(128,128)
  const int i0 = (type == 2) ? 128 : 0;
  const int j0 = (type == 0) ? 0 : 128;
  const bool diag = (type != 1);
  const int tid = threadIdx.x;
  const int wv = tid >> 6, lane = tid & 63;
  const int c = tid & 127, h = tid >> 7;    // staging: column, k-half (16 ks)
  const int k0 = blockIdx.y * KC;

  floatx16 acc[4];
#pragma unroll
  for (int t = 0; t < 4; ++t)
#pragma unroll
    for (int r = 0; r < 16; ++r) acc[t][r] = 0.f;
  float ssum = 0.f;

  const int mrow = lane & 31;
  const int kgrp = (lane >> 5) * 8;

  const float* colA0 = M + i0 + c;
  const float* colB0 = M + j0 + c;

  float va0[16], vb0[16], va1[16], vb1[16];

#define LOADSTEP(VA, VB, STEP)                                            \
  {                                                                       \
    const size_t kb = (size_t)(k0 + (STEP)*32 + h * 16) * 256;            \
    _Pragma("unroll") for (int u = 0; u < 16; ++u)                        \
        VA[u] = colA0[kb + (size_t)u * 256];                              \
    if (!diag) {                                                          \
      _Pragma("unroll") for (int u = 0; u < 16; ++u)                      \
          VB[u] = colB0[kb + (size_t)u * 256];                            \
    }                                                                     \
  }

#define BODYSTEP(VA, VB, PF)                                              \
  {                                                                       \
    if (diag) {                                                           \
      _Pragma("unroll") for (int u = 0; u < 16; ++u) ssum += VA[u];       \
    }                                                                     \
    ushort8 lo, hi;                                                       \
    _Pragma("unroll") for (int u = 0; u < 8; ++u) {                       \
      lo[u] = f2bf(VA[u]); hi[u] = f2bf(VA[u + 8]);                       \
    }                                                                     \
    *reinterpret_cast<ushort8*>(&Abf[c * LDA + h * 16]) = lo;             \
    *reinterpret_cast<ushort8*>(&Abf[c * LDA + h * 16 + 8]) = hi;         \
    if (!diag) {                                                          \
      _Pragma("unroll") for (int u = 0; u < 8; ++u) {                     \
        lo[u] = f2bf(VB[u]); hi[u] = f2bf(VB[u + 8]);                     \
      }                                                                   \
      *reinterpret_cast<ushort8*>(&Bbf[c * LDA + h * 16]) = lo;           \
      *reinterpret_cast<ushort8*>(&Bbf[c * LDA + h * 16 + 8]) = hi;       \
    }                                                                     \
    __syncthreads();                                                      \
    if ((PF) < NSTEP) LOADSTEP(VA, VB, PF);                               \
    const unsigned short* Bsrc = diag ? Abf : Bbf;                        \
    _Pragma("unroll") for (int sub = 0; sub < 2; ++sub) {                 \
      const int ko = sub * 16 + kgrp;                                     \
      bf16x8 a = __builtin_bit_cast(                                      \
          bf16x8, *reinterpret_cast<const ushort8*>(                      \
                      &Abf[(32 * wv + mrow) * LDA + ko]));                \
      _Pragma("unroll") for (int t = 0; t < 4; ++t) {                     \
        bf16x8 b = __builtin_bit_cast(                                    \
            bf16x8, *reinterpret_cast<const ushort8*>(                    \
                        &Bsrc[(32 * t + mrow) * LDA + ko]));              \
        acc[t] =                                                          \
            __builtin_amdgcn_mfma_f32_32x32x16_bf16(a, b, acc[t], 0, 0, 0); \
      }                                                                   \
    }                                                                     \
    __syncthreads();                                                      \
  }

  LOADSTEP(va0, vb0, 0);
  LOADSTEP(va1, vb1, 1);
  // steps 0..23 as 12 unrolled pairs, then step 24 (NSTEP==25)
  for (int sp = 0; sp < NSTEP - 1; sp += 2) {
    BODYSTEP(va0, vb0, sp + 2);
    BODYSTEP(va1, vb1, sp + 3);
  }
  BODYSTEP(va0, vb0, NSTEP);   // last step, no prefetch

#undef LOADSTEP
#undef BODYSTEP

  // epilogue: stream partial tile to Gp (lane-contiguous, dwordx4)
  float* base = Gp + (size_t)blockIdx.y * GP_CHUNK + type * 16384;
#pragma unroll
  for (int t = 0; t < 4; ++t) {
    float* dst = base + (((wv * 4 + t) * 64 + lane) * 16);
#pragma unroll
    for (int q = 0; q < 4; ++q) {
      float4 v = make_float4(acc[t][4 * q], acc[t][4 * q + 1],
                             acc[t][4 * q + 2], acc[t][4 * q + 3]);
      *reinterpret_cast<float4*>(dst + 4 * q) = v;
    }
  }
  if (diag) atomicAdd(&s[i0 + c], ssum);
}

// ---------------------------------------------------------------------------
// Kernel 1b: reduce Gp over chunks -> G (both quadrants; mirror for type 1)
// v2: 25 parallel accumulators (25 loads in flight, 10 dependency rounds)
// ---------------------------------------------------------------------------
__global__ __launch_bounds__(256) void reduce_g_kernel(
    const float* __restrict__ Gp, float* __restrict__ G) {
  const int e = blockIdx.x * 256 + threadIdx.x;   // [0, 49152)
  const float* p = Gp + e;
  float a[25];
#pragma unroll
  for (int i = 0; i < 25; ++i) a[i] = 0.f;
  for (int ch = 0; ch < NCHUNK; ch += 25) {
#pragma unroll
    for (int i = 0; i < 25; ++i) a[i] += p[(size_t)(ch + i) * GP_CHUNK];
  }
  float sum = 0.f;
#pragma unroll
  for (int i = 0; i < 25; ++i) sum += a[i];

  const int tile = e >> 14;
  const int r = e & 15;
  const int lane = (e >> 4) & 63;
  const int wvt = (e >> 10) & 15;
  const int wv = wvt >> 2, tt = wvt & 3;
  const int i0 = (tile == 2) ? 128 : 0;
  const int j0 = (tile == 0) ? 0 : 128;
  const int gr = i0 + 32 * wv + (r & 3) + 8 * (r >> 2) + 4 * (lane >> 5);
  const int gc = j0 + 32 * tt + (lane & 31);
  G[(size_t)gr * 256 + gc] = sum;
  if (tile == 1) G[(size_t)gc * 256 + gr] = sum;
}

// ---------------------------------------------------------------------------
// Kernel 2: layernorm of cls_logits -> p (row-major) and pT (transposed)
// ---------------------------------------------------------------------------
__global__ __launch_bounds__(64) void ln_kernel(const float* __restrict__ cls,
                                                float* __restrict__ p_row,
                                                float* __restrict__ pT) {
  const int c = blockIdx.x;
  const int t = threadIdx.x;
  const float* x = cls + (size_t)c * NC;
  float v0 = x[t];
  float v1 = x[t + 64];
  float v2 = (t < 72) ? x[t + 128] : 0.f;

  float sum = v0 + v1 + v2;
#pragma unroll
  for (int o = 32; o > 0; o >>= 1) sum += __shfl_xor(sum, o);
  const float mu = sum / (float)NC;

  float d0 = v0 - mu, d1 = v1 - mu, d2 = (t < 72) ? (v2 - mu) : 0.f;
  float sq = d0 * d0 + d1 * d1 + d2 * d2;
#pragma unroll
  for (int o = 32; o > 0; o >>= 1) sq += __shfl_xor(sq, o);
  const float var = sq / (float)NC;
  const float inv = 1.0f / sqrtf(var + LN_EPS);

  float p0 = d0 * inv, p1 = d1 * inv, p2 = d2 * inv;
  p_row[(size_t)c * NC + t] = p0;
  p_row[(size_t)c * NC + t + 64] = p1;
  pT[(size_t)t * C + c] = p0;
  pT[(size_t)(t + 64) * C + c] = p1;
  if (t < 72) {
    p_row[(size_t)c * NC + t + 128] = p2;
    pT[(size_t)(t + 128) * C + c] = p2;
  }
}

// ---------------------------------------------------------------------------
// Kernel 3: cond[i][j] = (dice > 0.4) && (sim > 0.5), packed 4x u64 per row.
// ---------------------------------------------------------------------------
__global__ __launch_bounds__(256) void cond_kernel(
    const float* __restrict__ G, const float* __restrict__ s,
    const float* __restrict__ p_row, const float* __restrict__ pT,
    unsigned long long* __restrict__ condW) {
  __shared__ float pi[NC];
  const int i = blockIdx.x;
  const int j = threadIdx.x;
  if (j < NC) pi[j] = p_row[(size_t)i * NC + j];
  __syncthreads();

  const float si = s[i];
  const float sj = s[j];
  const float g = G[(size_t)i * C + j];
  const float dice = 2.f * g / (si + sj);

  float a0 = 0.f, a1 = 0.f, a2 = 0.f, a3 = 0.f;
#pragma unroll 2
  for (int k = 0; k < NC; k += 4) {
    a0 = fmaf(pi[k + 0], pT[(size_t)(k + 0) * C + j], a0);
    a1 = fmaf(pi[k + 1], pT[(size_t)(k + 1) * C + j], a1);
    a2 = fmaf(pi[k + 2], pT[(size_t)(k + 2) * C + j], a2);
    a3 = fmaf(pi[k + 3], pT[(size_t)(k + 3) * C + j], a3);
  }
  const float acc = (a0 + a1) + (a2 + a3);

  const bool cnd = (dice > DICE_TH) && (acc > CLS_TH);
  unsigned long long m = __ballot(cnd);
  if ((j & 63) == 0) condW[i * 4 + (j >> 6)] = m;
}

// ---------------------------------------------------------------------------
// Kernel 4: sequential greedy scan (exact reference semantics), single wave.
// ---------------------------------------------------------------------------
__global__ __launch_bounds__(64) void scan_kernel(
    const unsigned long long* __restrict__ condW,
    float* __restrict__ out_labels, float* __restrict__ out_valid,
    int* __restrict__ mstart, int* __restrict__ members) {
  __shared__ unsigned long long cS[C * 4];
  __shared__ int cnt[C];
  __shared__ int ms[C + 1];
  const int t = threadIdx.x;

  for (int idx = t; idx < C * 4; idx += 64) cS[idx] = condW[idx];
  for (int idx = t; idx < C; idx += 64) cnt[idx] = 0;
  __syncthreads();

  unsigned long long asg[4] = {0ull, 0ull, 0ull, 0ull};
  int lab[4] = {-1, -1, -1, -1};   // lab[w] is label of column w*64 + t

  unsigned long long r0 = cS[0], r1 = cS[1], r2 = cS[2], r3 = cS[3];
  for (int i = 0; i < C; ++i) {
    const int nx = (i + 1 < C) ? (i + 1) * 4 : 0;
    unsigned long long n0 = cS[nx], n1 = cS[nx + 1], n2 = cS[nx + 2],
                       n3 = cS[nx + 3];
    const int w = i >> 6, b = i & 63;
    if (!((asg[w] >> b) & 1ull)) {   // leader i: take unassigned matches
      unsigned long long tk;
      tk = r0 & ~asg[0]; asg[0] |= tk; if ((tk >> t) & 1ull) lab[0] = i;
      tk = r1 & ~asg[1]; asg[1] |= tk; if ((tk >> t) & 1ull) lab[1] = i;
      tk = r2 & ~asg[2]; asg[2] |= tk; if ((tk >> t) & 1ull) lab[2] = i;
      tk = r3 & ~asg[3]; asg[3] |= tk; if ((tk >> t) & 1ull) lab[3] = i;
    }
    r0 = n0; r1 = n1; r2 = n2; r3 = n3;
  }

  // counts per leader
#pragma unroll
  for (int w = 0; w < 4; ++w)
    if (lab[w] >= 0) atomicAdd(&cnt[lab[w]], 1);
  __syncthreads();

  if (t == 0) {
    ms[0] = 0;
    for (int c2 = 0; c2 < C; ++c2) ms[c2 + 1] = ms[c2] + cnt[c2];
  }
  __syncthreads();
  for (int idx = t; idx < C; idx += 64) cnt[idx] = ms[idx];
  __syncthreads();
#pragma unroll
  for (int w = 0; w < 4; ++w) {
    if (lab[w] >= 0) {
      int pos = atomicAdd(&cnt[lab[w]], 1);
      members[pos] = w * 64 + t;
    }
  }
#pragma unroll
  for (int w = 0; w < 4; ++w) {
    const int col = w * 64 + t;
    out_labels[col] = (float)lab[w];
    out_valid[col] = (ms[col + 1] > ms[col]) ? 1.0f : 0.0f;
  }
  for (int idx = t; idx < C + 1; idx += 64) mstart[idx] = ms[idx];
}

// ---------------------------------------------------------------------------
// Kernel 5: new_masks[p][c] = valid(c) ? max over members of M[p][j] : 0
// v3: thread owns 4 rows x 4 cols -> float4 stores; row loads issued first.
// ---------------------------------------------------------------------------
__global__ __launch_bounds__(256) void merge_masks_kernel(
    const float* __restrict__ M, const int* __restrict__ mstart,
    const int* __restrict__ members, float* __restrict__ out_masks) {
  __shared__ float rows[16 * 256];
  __shared__ int msS[C + 1];
  __shared__ int memS[C];
  const int tid = threadIdx.x;
  const size_t p0 = (size_t)blockIdx.x * 16;

  // issue the big row loads first
  const float4* src = reinterpret_cast<const float4*>(M + p0 * 256);
  float4 v0 = src[0 * 256 + tid];
  float4 v1 = src[1 * 256 + tid];
  float4 v2 = src[2 * 256 + tid];
  float4 v3 = src[3 * 256 + tid];
  msS[tid] = mstart[tid];
  if (tid == 0) msS[C] = mstart[C];
  memS[tid] = members[tid];
  reinterpret_cast<float4*>(rows)[0 * 256 + tid] = v0;
  reinterpret_cast<float4*>(rows)[1 * 256 + tid] = v1;
  reinterpret_cast<float4*>(rows)[2 * 256 + tid] = v2;
  reinterpret_cast<float4*>(rows)[3 * 256 + tid] = v3;
  __syncthreads();

  // thread owns cols 4*(tid&63)..+3, rows 4*(tid>>6)..+3
  const int cb = (tid & 63) * 4;
  const int rb = (tid >> 6) * 4;
  float mx[4][4];   // [row][col]
#pragma unroll
  for (int r = 0; r < 4; ++r)
#pragma unroll
    for (int cc = 0; cc < 4; ++cc) mx[r][cc] = 0.f;

#pragma unroll
  for (int cc = 0; cc < 4; ++cc) {
    const int col = cb + cc;
    const int st = msS[col], en = msS[col + 1];
    for (int k = st; k < en; ++k) {
      const int mm = memS[k];
#pragma unroll
      for (int r = 0; r < 4; ++r)
        mx[r][cc] = fmaxf(mx[r][cc], rows[(rb + r) * 256 + mm]);
    }
  }
#pragma unroll
  for (int r = 0; r < 4; ++r) {
    float4 v = make_float4(mx[r][0], mx[r][1], mx[r][2], mx[r][3]);
    *reinterpret_cast<float4*>(&out_masks[(p0 + rb + r) * 256 + cb]) = v;
  }
}

// ---------------------------------------------------------------------------
// Kernel 6: new_cls[c][k] = valid(c) ? max over members of cls[j][k] : 0
// ---------------------------------------------------------------------------
__global__ __launch_bounds__(256) void merge_cls_kernel(
    const float* __restrict__ cls, const int* __restrict__ mstart,
    const int* __restrict__ members, float* __restrict__ out_cls) {
  __shared__ int se[2];
  const int c = blockIdx.x;
  const int t = threadIdx.x;
  if (t < 2) se[t] = mstart[c + t];
  __syncthreads();
  const int st = se[0], en = se[1];
  if (t < NC) {
    float mx = 0.f;
    if (en > st) {
      mx = cls[(size_t)members[st] * NC + t];
      for (int k = st + 1; k < en; ++k)
        mx = fmaxf(mx, cls[(size_t)members[k] * NC + t]);
    }
    out_cls[(size_t)c * NC + t] = mx;
  }
}

// ---------------------------------------------------------------------------
extern "C" void kernel_launch(void* const* d_in, const int* in_sizes, int n_in,
                              void* d_out, int out_size, void* d_ws,
                              size_t ws_size, hipStream_t stream) {
  const float* M = (const float*)d_in[0];    // [P, C] fp32
  const float* cls = (const float*)d_in[1];  // [C, NC] fp32

  float* out = (float*)d_out;
  char* ws = (char*)d_ws;
  float* Gp = (float*)(ws + WS_GP);
  float* G = (float*)(ws + WS_G);
  float* s = (float*)(ws + WS_S);
  float* p_row = (float*)(ws + WS_PROW);
  float* pT = (float*)(ws + WS_PT);
  unsigned long long* condW = (unsigned long long*)(ws + WS_COND);
  int* mstart = (int*)(ws + WS_MSTART);
  int* members = (int*)(ws + WS_MEMBERS);

  float* out_labels = out;
  float* out_valid = out + 256;
  float* out_masks = out + 512;
  float* out_cls = out + 512 + (size_t)P * 256;

  // zero only the s accumulator (G is fully written by reduce_g)
  hipMemsetAsync(ws + WS_S, 0, 1024, stream);

  gram_mfma_kernel<<<dim3(3, NCHUNK), 256, 0, stream>>>(M, Gp, s);
  reduce_g_kernel<<<GP_CHUNK / 256, 256, 0, stream>>>(Gp, G);
  ln_kernel<<<C, 64, 0, stream>>>(cls, p_row, pT);
  cond_kernel<<<C, 256, 0, stream>>>(G, s, p_row, pT, condW);
  scan_kernel<<<1, 64, 0, stream>>>(condW, out_labels, out_valid, mstart,
                                    members);
  merge_masks_kernel<<<P / 16, 256, 0, stream>>>(M, mstart, members, out_masks);
  merge_cls_kernel<<<C, 256, 0, stream>>>(cls, mstart, members, out_cls);
}

// Round 6
// 455.373 us; speedup vs baseline: 1.1828x; 1.1828x over previous
//
#include <hip/hip_runtime.h>
#include <cstdint>
#include <cstddef>

// Problem constants (from reference setup_inputs)
constexpr int P  = 200000;   // points
constexpr int C  = 256;      // clicks
constexpr int NC = 200;      // classes
#define DICE_TH 0.4f
#define CLS_TH  0.5f
#define LN_EPS  1e-5f

// gram split-K config: KC * NCHUNK == P, KC % 32 == 0
constexpr int KC = 800;
constexpr int NCHUNK = 250;
constexpr int NSTEP = KC / 32;        // 25
constexpr int GP_CHUNK = 48 * 1024;   // floats per chunk (48 subtiles x 1024)

// workspace byte offsets (Gp partials first; total ~49.9 MB)
constexpr size_t WS_GP      = 0;                         // 250*49152*4 = 49,152,000
constexpr size_t WS_G       = 49152000;                  // 262144
constexpr size_t WS_S       = WS_G + 262144;             // 1024
constexpr size_t WS_PROW    = WS_S + 1024;               // 204800
constexpr size_t WS_PT      = WS_PROW + 204800;          // 204800
constexpr size_t WS_COND    = WS_PT + 204800;            // 8192
constexpr size_t WS_MSTART  = WS_COND + 8192;            // 1028
constexpr size_t WS_MEMBERS = WS_MSTART + 1280;          // 1024

typedef float floatx16 __attribute__((ext_vector_type(16)));
typedef __bf16 bf16x8 __attribute__((ext_vector_type(8)));
typedef unsigned short ushort8 __attribute__((ext_vector_type(8)));

__device__ __forceinline__ unsigned short f2bf(float f) {
  unsigned u = __builtin_bit_cast(unsigned, f);
  unsigned r = u + 0x7FFFu + ((u >> 16) & 1u);   // RNE
  return (unsigned short)(r >> 16);
}

// ---------------------------------------------------------------------------
// Kernel 1: G = M^T M via bf16 MFMA, full-row blocks: each block stages the
// ENTIRE 256-col k-slice once (M read exactly 1x = 205 MB) and computes all
// three needed quadrants (0,0),(0,1),(1,1). 12 subtiles/wave = 192 acc regs;
// __launch_bounds__(256,1) guarantees no spill (1 wave/SIMD by design —
// latency hidden by the 32-deep register prefetch, 32 KB/CU in flight).
// LDS: [col][k] bf16 stride 40 — the exact pattern R2 measured at 0 bank
// conflicts for both ushort8 writes and b128 frag reads.
// ---------------------------------------------------------------------------
constexpr int LDA = 40;

__global__ __launch_bounds__(256, 1) void gram_full_kernel(
    const float* __restrict__ M, float* __restrict__ Gp,
    float* __restrict__ s) {
  __shared__ unsigned short Bls[256 * LDA];   // 20.5 KB

  const int tid = threadIdx.x;
  const int wv = tid >> 6, lane = tid & 63;
  const int k0 = blockIdx.x * KC;
  const int mrow = lane & 31;
  const int kgrp = (lane >> 5) * 8;

  floatx16 acc[12];
#pragma unroll
  for (int t = 0; t < 12; ++t)
#pragma unroll
    for (int r = 0; r < 16; ++r) acc[t][r] = 0.f;
  float ssum = 0.f;

  const float* col0 = M + tid;   // this thread's column
  float va[32];
  {
    const size_t kb = (size_t)k0 * 256;
#pragma unroll
    for (int u = 0; u < 32; ++u) va[u] = col0[kb + (size_t)u * 256];
  }

#define FRAG(ROW, KO)                                                \
  __builtin_bit_cast(bf16x8, *reinterpret_cast<const ushort8*>(      \
                                 &Bls[((ROW) + mrow) * LDA + (KO)]))

  for (int step = 0; step < NSTEP; ++step) {
    // convert current regs -> LDS (+ column sum)
#pragma unroll
    for (int u = 0; u < 32; ++u) ssum += va[u];
#pragma unroll
    for (int q = 0; q < 4; ++q) {
      ushort8 t8;
#pragma unroll
      for (int m = 0; m < 8; ++m) t8[m] = f2bf(va[q * 8 + m]);
      *reinterpret_cast<ushort8*>(&Bls[tid * LDA + q * 8]) = t8;
    }
    __syncthreads();

    // prefetch next step while MFMAs run
    if (step + 1 < NSTEP) {
      const size_t kb = (size_t)(k0 + (step + 1) * 32) * 256;
#pragma unroll
      for (int u = 0; u < 32; ++u) va[u] = col0[kb + (size_t)u * 256];
    }

#pragma unroll
    for (int sub = 0; sub < 2; ++sub) {
      const int ko = sub * 16 + kgrp;
      bf16x8 a0 = FRAG(32 * wv, ko);          // rows 0..127 band
      bf16x8 a1 = FRAG(128 + 32 * wv, ko);    // rows 128..255 band
#pragma unroll
      for (int cb = 0; cb < 4; ++cb) {
        bf16x8 blo = FRAG(32 * cb, ko);
        acc[cb] = __builtin_amdgcn_mfma_f32_32x32x16_bf16(a0, blo, acc[cb],
                                                          0, 0, 0);
      }
#pragma unroll
      for (int cb = 0; cb < 4; ++cb) {
        bf16x8 bhi = FRAG(128 + 32 * cb, ko);
        acc[4 + cb] = __builtin_amdgcn_mfma_f32_32x32x16_bf16(
            a0, bhi, acc[4 + cb], 0, 0, 0);
        acc[8 + cb] = __builtin_amdgcn_mfma_f32_32x32x16_bf16(
            a1, bhi, acc[8 + cb], 0, 0, 0);
      }
    }
    __syncthreads();
  }
#undef FRAG

  // epilogue: stream 48 subtiles (12 per wave) to Gp, lane-contiguous
  float* base = Gp + (size_t)blockIdx.x * GP_CHUNK;
#pragma unroll
  for (int t = 0; t < 12; ++t) {
    float* dst = base + (size_t)(wv * 12 + t) * 1024 + lane * 16;
#pragma unroll
    for (int q = 0; q < 4; ++q) {
      float4 v = make_float4(acc[t][4 * q], acc[t][4 * q + 1],
                             acc[t][4 * q + 2], acc[t][4 * q + 3]);
      *reinterpret_cast<float4*>(dst + 4 * q) = v;
    }
  }
  atomicAdd(&s[tid], ssum);
}

// ---------------------------------------------------------------------------
// Kernel 1b: reduce Gp over chunks -> G. Decodes the 48-subtile layout:
// sub = wv*12 + t; t 0..3 -> quad (0,0), 4..7 -> (0,1) (mirror to (1,0)),
// 8..11 -> (1,1). C/D layout: col=lane&31, row=(r&3)+8*(r>>2)+4*(lane>>5).
// 25 parallel accumulators for load ILP.
// ---------------------------------------------------------------------------
__global__ __launch_bounds__(256) void reduce_g_kernel(
    const float* __restrict__ Gp, float* __restrict__ G) {
  const int e = blockIdx.x * 256 + threadIdx.x;   // [0, 49152)
  const float* p = Gp + e;
  float a[25];
#pragma unroll
  for (int i = 0; i < 25; ++i) a[i] = 0.f;
  for (int ch = 0; ch < NCHUNK; ch += 25) {
#pragma unroll
    for (int i = 0; i < 25; ++i) a[i] += p[(size_t)(ch + i) * GP_CHUNK];
  }
  float sum = 0.f;
#pragma unroll
  for (int i = 0; i < 25; ++i) sum += a[i];

  const int sub = e >> 10;        // 0..47
  const int idx = e & 1023;
  const int lane = idx >> 4;
  const int r = idx & 15;
  const int wv = sub / 12;
  const int t = sub % 12;
  int rowband, colband;
  bool mirror = false;
  if (t < 4) {
    rowband = 32 * wv; colband = 32 * t;
  } else if (t < 8) {
    rowband = 32 * wv; colband = 128 + 32 * (t - 4); mirror = true;
  } else {
    rowband = 128 + 32 * wv; colband = 128 + 32 * (t - 8);
  }
  const int gr = rowband + (r & 3) + 8 * (r >> 2) + 4 * (lane >> 5);
  const int gc = colband + (lane & 31);
  G[(size_t)gr * 256 + gc] = sum;
  if (mirror) G[(size_t)gc * 256 + gr] = sum;
}

// ---------------------------------------------------------------------------
// Kernel 2: layernorm of cls_logits -> p (row-major) and pT (transposed)
// ---------------------------------------------------------------------------
__global__ __launch_bounds__(64) void ln_kernel(const float* __restrict__ cls,
                                                float* __restrict__ p_row,
                                                float* __restrict__ pT) {
  const int c = blockIdx.x;
  const int t = threadIdx.x;
  const float* x = cls + (size_t)c * NC;
  float v0 = x[t];
  float v1 = x[t + 64];
  float v2 = (t < 72) ? x[t + 128] : 0.f;

  float sum = v0 + v1 + v2;
#pragma unroll
  for (int o = 32; o > 0; o >>= 1) sum += __shfl_xor(sum, o);
  const float mu = sum / (float)NC;

  float d0 = v0 - mu, d1 = v1 - mu, d2 = (t < 72) ? (v2 - mu) : 0.f;
  float sq = d0 * d0 + d1 * d1 + d2 * d2;
#pragma unroll
  for (int o = 32; o > 0; o >>= 1) sq += __shfl_xor(sq, o);
  const float var = sq / (float)NC;
  const float inv = 1.0f / sqrtf(var + LN_EPS);

  float p0 = d0 * inv, p1 = d1 * inv, p2 = d2 * inv;
  p_row[(size_t)c * NC + t] = p0;
  p_row[(size_t)c * NC + t + 64] = p1;
  pT[(size_t)t * C + c] = p0;
  pT[(size_t)(t + 64) * C + c] = p1;
  if (t < 72) {
    p_row[(size_t)c * NC + t + 128] = p2;
    pT[(size_t)(t + 128) * C + c] = p2;
  }
}

// ---------------------------------------------------------------------------
// Kernel 3: cond[i][j] = (dice > 0.4) && (sim > 0.5), packed 4x u64 per row.
// ---------------------------------------------------------------------------
__global__ __launch_bounds__(256) void cond_kernel(
    const float* __restrict__ G, const float* __restrict__ s,
    const float* __restrict__ p_row, const float* __restrict__ pT,
    unsigned long long* __restrict__ condW) {
  __shared__ float pi[NC];
  const int i = blockIdx.x;
  const int j = threadIdx.x;
  if (j < NC) pi[j] = p_row[(size_t)i * NC + j];
  __syncthreads();

  const float si = s[i];
  const float sj = s[j];
  const float g = G[(size_t)i * C + j];
  const float dice = 2.f * g / (si + sj);

  float a0 = 0.f, a1 = 0.f, a2 = 0.f, a3 = 0.f;
#pragma unroll 2
  for (int k = 0; k < NC; k += 4) {
    a0 = fmaf(pi[k + 0], pT[(size_t)(k + 0) * C + j], a0);
    a1 = fmaf(pi[k + 1], pT[(size_t)(k + 1) * C + j], a1);
    a2 = fmaf(pi[k + 2], pT[(size_t)(k + 2) * C + j], a2);
    a3 = fmaf(pi[k + 3], pT[(size_t)(k + 3) * C + j], a3);
  }
  const float acc = (a0 + a1) + (a2 + a3);

  const bool cnd = (dice > DICE_TH) && (acc > CLS_TH);
  unsigned long long m = __ballot(cnd);
  if ((j & 63) == 0) condW[i * 4 + (j >> 6)] = m;
}

// ---------------------------------------------------------------------------
// Kernel 4: sequential greedy scan (exact reference semantics), single wave.
// ---------------------------------------------------------------------------
__global__ __launch_bounds__(64) void scan_kernel(
    const unsigned long long* __restrict__ condW,
    float* __restrict__ out_labels, float* __restrict__ out_valid,
    int* __restrict__ mstart, int* __restrict__ members) {
  __shared__ unsigned long long cS[C * 4];
  __shared__ int cnt[C];
  __shared__ int ms[C + 1];
  const int t = threadIdx.x;

  for (int idx = t; idx < C * 4; idx += 64) cS[idx] = condW[idx];
  for (int idx = t; idx < C; idx += 64) cnt[idx] = 0;
  __syncthreads();

  unsigned long long asg[4] = {0ull, 0ull, 0ull, 0ull};
  int lab[4] = {-1, -1, -1, -1};   // lab[w] is label of column w*64 + t

  unsigned long long r0 = cS[0], r1 = cS[1], r2 = cS[2], r3 = cS[3];
  for (int i = 0; i < C; ++i) {
    const int nx = (i + 1 < C) ? (i + 1) * 4 : 0;
    unsigned long long n0 = cS[nx], n1 = cS[nx + 1], n2 = cS[nx + 2],
                       n3 = cS[nx + 3];
    const int w = i >> 6, b = i & 63;
    if (!((asg[w] >> b) & 1ull)) {   // leader i: take unassigned matches
      unsigned long long tk;
      tk = r0 & ~asg[0]; asg[0] |= tk; if ((tk >> t) & 1ull) lab[0] = i;
      tk = r1 & ~asg[1]; asg[1] |= tk; if ((tk >> t) & 1ull) lab[1] = i;
      tk = r2 & ~asg[2]; asg[2] |= tk; if ((tk >> t) & 1ull) lab[2] = i;
      tk = r3 & ~asg[3]; asg[3] |= tk; if ((tk >> t) & 1ull) lab[3] = i;
    }
    r0 = n0; r1 = n1; r2 = n2; r3 = n3;
  }

  // counts per leader
#pragma unroll
  for (int w = 0; w < 4; ++w)
    if (lab[w] >= 0) atomicAdd(&cnt[lab[w]], 1);
  __syncthreads();

  if (t == 0) {
    ms[0] = 0;
    for (int c2 = 0; c2 < C; ++c2) ms[c2 + 1] = ms[c2] + cnt[c2];
  }
  __syncthreads();
  for (int idx = t; idx < C; idx += 64) cnt[idx] = ms[idx];
  __syncthreads();
#pragma unroll
  for (int w = 0; w < 4; ++w) {
    if (lab[w] >= 0) {
      int pos = atomicAdd(&cnt[lab[w]], 1);
      members[pos] = w * 64 + t;
    }
  }
#pragma unroll
  for (int w = 0; w < 4; ++w) {
    const int col = w * 64 + t;
    out_labels[col] = (float)lab[w];
    out_valid[col] = (ms[col + 1] > ms[col]) ? 1.0f : 0.0f;
  }
  for (int idx = t; idx < C + 1; idx += 64) mstart[idx] = ms[idx];
}

// ---------------------------------------------------------------------------
// Kernel 5: new_masks[p][c] = valid(c) ? max over members of M[p][j] : 0
// 16 rows per block staged in LDS (R3-vintage known-good version)
// ---------------------------------------------------------------------------
__global__ __launch_bounds__(256) void merge_masks_kernel(
    const float* __restrict__ M, const int* __restrict__ mstart,
    const int* __restrict__ members, float* __restrict__ out_masks) {
  __shared__ float rows[16 * 256];
  __shared__ int msS[C + 1];
  __shared__ int memS[C];
  const int tid = threadIdx.x;
  const size_t p0 = (size_t)blockIdx.x * 16;

  msS[tid] = mstart[tid];
  if (tid == 0) msS[C] = mstart[C];
  memS[tid] = members[tid];

  const float4* src = reinterpret_cast<const float4*>(M + p0 * 256);
#pragma unroll
  for (int it = 0; it < 4; ++it)
    reinterpret_cast<float4*>(rows)[it * 256 + tid] = src[it * 256 + tid];
  __syncthreads();

  const int st = msS[tid], en = msS[tid + 1];
  float mx[16];
  if (en > st) {
    const int m0 = memS[st];
#pragma unroll
    for (int r = 0; r < 16; ++r) mx[r] = rows[r * 256 + m0];
    for (int k = st + 1; k < en; ++k) {
      const int mm = memS[k];
#pragma unroll
      for (int r = 0; r < 16; ++r) mx[r] = fmaxf(mx[r], rows[r * 256 + mm]);
    }
  } else {
#pragma unroll
    for (int r = 0; r < 16; ++r) mx[r] = 0.f;
  }
#pragma unroll
  for (int r = 0; r < 16; ++r) out_masks[(p0 + r) * 256 + tid] = mx[r];
}

// ---------------------------------------------------------------------------
// Kernel 6: new_cls[c][k] = valid(c) ? max over members of cls[j][k] : 0
// ---------------------------------------------------------------------------
__global__ __launch_bounds__(256) void merge_cls_kernel(
    const float* __restrict__ cls, const int* __restrict__ mstart,
    const int* __restrict__ members, float* __restrict__ out_cls) {
  __shared__ int se[2];
  const int c = blockIdx.x;
  const int t = threadIdx.x;
  if (t < 2) se[t] = mstart[c + t];
  __syncthreads();
  const int st = se[0], en = se[1];
  if (t < NC) {
    float mx = 0.f;
    if (en > st) {
      mx = cls[(size_t)members[st] * NC + t];
      for (int k = st + 1; k < en; ++k)
        mx = fmaxf(mx, cls[(size_t)members[k] * NC + t]);
    }
    out_cls[(size_t)c * NC + t] = mx;
  }
}

// ---------------------------------------------------------------------------
extern "C" void kernel_launch(void* const* d_in, const int* in_sizes, int n_in,
                              void* d_out, int out_size, void* d_ws,
                              size_t ws_size, hipStream_t stream) {
  const float* M = (const float*)d_in[0];    // [P, C] fp32
  const float* cls = (const float*)d_in[1];  // [C, NC] fp32

  float* out = (float*)d_out;
  char* ws = (char*)d_ws;
  float* Gp = (float*)(ws + WS_GP);
  float* G = (float*)(ws + WS_G);
  float* s = (float*)(ws + WS_S);
  float* p_row = (float*)(ws + WS_PROW);
  float* pT = (float*)(ws + WS_PT);
  unsigned long long* condW = (unsigned long long*)(ws + WS_COND);
  int* mstart = (int*)(ws + WS_MSTART);
  int* members = (int*)(ws + WS_MEMBERS);

  float* out_labels = out;
  float* out_valid = out + 256;
  float* out_masks = out + 512;
  float* out_cls = out + 512 + (size_t)P * 256;

  // zero only the s accumulator (G is fully written by reduce_g)
  hipMemsetAsync(ws + WS_S, 0, 1024, stream);

  gram_full_kernel<<<NCHUNK, 256, 0, stream>>>(M, Gp, s);
  reduce_g_kernel<<<GP_CHUNK / 1024 * 4, 256, 0, stream>>>(Gp, G);
  ln_kernel<<<C, 64, 0, stream>>>(cls, p_row, pT);
  cond_kernel<<<C, 256, 0, stream>>>(G, s, p_row, pT, condW);
  scan_kernel<<<1, 64, 0, stream>>>(condW, out_labels, out_valid, mstart,
                                    members);
  merge_masks_kernel<<<P / 16, 256, 0, stream>>>(M, mstart, members, out_masks);
  merge_cls_kernel<<<C, 256, 0, stream>>>(cls, mstart, members, out_cls);
}